// Round 10
// baseline (502.583 us; speedup 1.0000x reference)
//
#include <hip/hip_runtime.h>
#include <hip/hip_bf16.h>

// MHA: B=4 S=2048 D=1024 H=16 DK=64. fp32 in/out, bf16 MFMA internally.

typedef __attribute__((ext_vector_type(8))) short bf16x8;
typedef __attribute__((ext_vector_type(4))) float f32x4;

static __device__ __forceinline__ unsigned short f2bf(float f) {
  union { __hip_bfloat16 h; unsigned short u; } cv;
  cv.h = __float2bfloat16(f);
  return cv.u;
}

// hardware packed f32->bf16 (RNE) — T12 recipe; no builtin on gfx950
static __device__ __forceinline__ unsigned int cvtpk(float lo, float hi) {
  unsigned int r;
  asm("v_cvt_pk_bf16_f32 %0, %1, %2" : "=v"(r) : "v"(lo), "v"(hi));
  return r;
}

// gfx950 cross-lane quad swaps. pl32: D[32:63]<->S[0:31]. pl16: D[16:31]<->S[0:15], D[48:63]<->S[32:47].
static __device__ __forceinline__ void pl32swap(unsigned int& a, unsigned int& b) {
  asm volatile("v_permlane32_swap_b32 %0, %1" : "+v"(a), "+v"(b));
}
static __device__ __forceinline__ void pl16swap(unsigned int& a, unsigned int& b) {
  asm volatile("v_permlane16_swap_b32 %0, %1" : "+v"(a), "+v"(b));
}

static __device__ __forceinline__ void gload_lds16(const void* g, void* l) {
  __builtin_amdgcn_global_load_lds(
      (const __attribute__((address_space(1))) unsigned int*)g,
      (__attribute__((address_space(3))) unsigned int*)l, 16, 0, 0);
}

// ---------------------------------------------------------------- converts (batched)
template<int NJ>
struct CvtJobs { const float* in[NJ]; unsigned short* out[NJ]; int n; };

template<int NJ>
__global__ __launch_bounds__(256) void cvt_batch(CvtJobs<NJ> jobs) {
  const float* __restrict__ in = jobs.in[blockIdx.y];
  unsigned short* __restrict__ out = jobs.out[blockIdx.y];
  int i = (blockIdx.x * 256 + threadIdx.x) * 4;
  if (i + 3 < jobs.n) {
    float4 v = *(const float4*)(in + i);
    ushort4 o;
    o.x = f2bf(v.x); o.y = f2bf(v.y); o.z = f2bf(v.z); o.w = f2bf(v.w);
    *(ushort4*)(out + i) = o;
  }
}

// ---------------------------------------------------------------- GEMM (B^T)
// C[M,N] = A[M,K] * Bw[N,K]^T + bias, bf16 inputs, fp32 accum.
// MODE 4: Q&K merged via blockIdx.z (z=0: Q, *0.125*log2e for exp2 softmax; z=1: K)
// MODE 2: V^T [B,H,DK,S]; gm=channel, gn=token, bias[gm]
// MODE 3: fp32 [M,N], bias[gn]
template<int MODE>
__global__ __launch_bounds__(256) void gemm_bt(const unsigned short* __restrict__ A_,
                                               const unsigned short* __restrict__ Bw_,
                                               const float* __restrict__ bias,
                                               const float* __restrict__ bias1,
                                               void* __restrict__ outp,
                                               int M, int N, int K) {
  __shared__ unsigned short As[128 * 32];
  __shared__ unsigned short Bs[128 * 32];
  const int tid = threadIdx.x;
  const int w = tid >> 6, lane = tid & 63;
  const int wr = w >> 1, wc = w & 1;
  const int fr = lane & 15, fg = lane >> 4;

  const unsigned short* A = A_;
  const unsigned short* Bw = Bw_;
  float scale = 1.f;
  unsigned short* out16 = (unsigned short*)outp;
  if (MODE == 4) {
    const int z = blockIdx.z;
    A += (size_t)z * (8192 * 1024);
    Bw += (size_t)z * (1024 * 1024);
    out16 += (size_t)z * (8192 * 1024);
    if (z == 0) scale = 0.18033688011f;  // 0.125 * log2(e): softmax uses exp2
    else bias = bias1;
  }

  // XCD-aware swizzle (bijective; nwg%8==0): consecutive by-rows per XCD.
  int bx, by;
  if (MODE != 2) {
    const int nwg = gridDim.x * gridDim.y;
    const int lin = blockIdx.y * gridDim.x + blockIdx.x;
    const int nb = (lin & 7) * (nwg >> 3) + (lin >> 3);
    bx = nb % gridDim.x; by = nb / gridDim.x;
  } else {
    bx = blockIdx.x; by = blockIdx.y;
  }
  const int m0 = by * 128, n0 = bx * 128;

  f32x4 acc[4][4] = {};
  const int e0 = (w * 2) * 512 + lane * 8;

  for (int kt = 0; kt < K; kt += 32) {
#pragma unroll
    for (int i = 0; i < 2; ++i) {
      const int e = e0 + i * 512;
      const int row = e >> 5, kk = e & 31;
      gload_lds16(A + (size_t)(m0 + row) * K + kt + kk, (void*)(As + e));
      gload_lds16(Bw + (size_t)(n0 + row) * K + kt + kk, (void*)(Bs + e));
    }
    __syncthreads();
    bf16x8 af[4], bfr[4];
#pragma unroll
    for (int m = 0; m < 4; ++m)
      af[m] = *(const bf16x8*)(As + (wr * 64 + m * 16 + fr) * 32 + fg * 8);
#pragma unroll
    for (int n = 0; n < 4; ++n)
      bfr[n] = *(const bf16x8*)(Bs + (wc * 64 + n * 16 + fr) * 32 + fg * 8);
#pragma unroll
    for (int m = 0; m < 4; ++m)
#pragma unroll
      for (int n = 0; n < 4; ++n)
        acc[m][n] = __builtin_amdgcn_mfma_f32_16x16x32_bf16(af[m], bfr[n], acc[m][n], 0, 0, 0);
    __syncthreads();
  }

#pragma unroll
  for (int m = 0; m < 4; ++m) {
#pragma unroll
    for (int n = 0; n < 4; ++n) {
      const int gn = n0 + wc * 64 + n * 16 + fr;
#pragma unroll
      for (int r = 0; r < 4; ++r) {
        const int gm = m0 + wr * 64 + m * 16 + fg * 4 + r;
        float val = acc[m][n][r];
        if (MODE == 2) val += bias[gm]; else val += bias[gn];
        if (MODE == 4) {
          val *= scale;
          size_t idx = ((size_t)((gm >> 11) * 16 + (gn >> 6)) * 2048 + (gm & 2047)) * 64 + (gn & 63);
          out16[idx] = f2bf(val);
        } else if (MODE == 2) {
          size_t idx = ((size_t)((gn >> 11) * 16 + (gm >> 6)) * 64 + (gm & 63)) * 2048 + (gn & 2047);
          out16[idx] = f2bf(val);
        } else {
          ((float*)outp)[(size_t)gm * N + gn] = val;
        }
      }
    }
  }
}

// ---------------------------------------------------------------- flash attention
// Qh,Kh: [B*H, S, DK] bf16 (Q pre-scaled by 0.125*log2e); Vt: [B*H, DK, S] bf16.
// Out Xa: [B, S, D] bf16. Barrier-free, LDS-free. Fixed-max softmax via exp2,
// P-in-register via permlane, row-sum on the MFMA pipe (P x ones).
// Register-frugal 32-k-chunk loop: only kh[2][2]+vk[4] (32 regs) in flight,
// sc is 8 regs — peak live ~120 VGPR -> 4 waves/SIMD (grid 1024 x 4 waves).
// Occupancy, not scheduling, hides the L2 latency.
// Block: 4 waves x 32 q. Grid: 1024, XCD-swizzled.
__global__ __launch_bounds__(256, 4) void attn_kernel(const unsigned short* __restrict__ Qh,
                                                      const unsigned short* __restrict__ Kh,
                                                      const unsigned short* __restrict__ Vt,
                                                      unsigned short* __restrict__ Xa) {
  const int S = 2048, DK = 64;
  const int tid = threadIdx.x;
  const int w = tid >> 6, lane = tid & 63;
  const int fr = lane & 15, fg = lane >> 4;

  // XCD swizzle: 1024 blocks; each XCD owns 8 bh (K+V = 4 MB -> one XCD's L2).
  const int bid = blockIdx.x;
  const int xcd = bid & 7, slot = bid >> 3;   // slot 0..127
  const int bh = xcd * 8 + (slot >> 4);       // 8 bh per XCD
  const int qblk = slot & 15;
  const int q0 = qblk * 128 + w * 32;

  const unsigned short* Qp = Qh + (size_t)bh * S * DK;
  const unsigned short* Kp = Kh + (size_t)bh * S * DK;
  const unsigned short* Vp = Vt + (size_t)bh * DK * S;

  // persistent Q fragments (B-operand, rows q): 2 q-tiles x 2 ks = 16 regs
  bf16x8 qf[2][2];
#pragma unroll
  for (int nt = 0; nt < 2; ++nt)
#pragma unroll
    for (int ks = 0; ks < 2; ++ks)
      qf[nt][ks] = *(const bf16x8*)(Qp + (size_t)(q0 + nt * 16 + fr) * DK + ks * 32 + fg * 8);

  bf16x8 ones;
#pragma unroll
  for (int j = 0; j < 8; ++j) ones[j] = (short)0x3F80;  // bf16 1.0

  f32x4 xacc[2][4] = {};
  f32x4 xsum[2] = {};

  // 32-k-chunk loop: per iter, K rows [kv2, kv2+32) and V^T cols [kv2, kv2+32).
  for (int kv2 = 0; kv2 < S; kv2 += 32) {
    // K fragments (A-operand, rows k): mt in {0,1} -> 8 loads, 16 regs
    bf16x8 kh[2][2];
#pragma unroll
    for (int mt = 0; mt < 2; ++mt)
#pragma unroll
      for (int ks = 0; ks < 2; ++ks)
        kh[mt][ks] = *(const bf16x8*)(Kp + (size_t)(kv2 + mt * 16 + fr) * DK + ks * 32 + fg * 8);
    // V^T fragments (B-operand, rows d, k-slice cols): 4 loads, 16 regs
    bf16x8 vk[4];
#pragma unroll
    for (int dn = 0; dn < 4; ++dn)
      vk[dn] = *(const bf16x8*)(Vp + (size_t)(dn * 16 + fr) * S + kv2 + fg * 8);

#pragma unroll
    for (int nt = 0; nt < 2; ++nt) {
      // QK^T swapped: lane holds q=nt*16+fr (col), k=mt*16+fg*4+r (row)
      f32x4 s0, s1;
      __builtin_amdgcn_s_setprio(1);
      s0 = __builtin_amdgcn_mfma_f32_16x16x32_bf16(kh[0][0], qf[nt][0],
                                                   (f32x4){0.f, 0.f, 0.f, 0.f}, 0, 0, 0);
      s0 = __builtin_amdgcn_mfma_f32_16x16x32_bf16(kh[0][1], qf[nt][1], s0, 0, 0, 0);
      s1 = __builtin_amdgcn_mfma_f32_16x16x32_bf16(kh[1][0], qf[nt][0],
                                                   (f32x4){0.f, 0.f, 0.f, 0.f}, 0, 0, 0);
      s1 = __builtin_amdgcn_mfma_f32_16x16x32_bf16(kh[1][1], qf[nt][1], s1, 0, 0, 0);
      __builtin_amdgcn_s_setprio(0);

      // p = exp2(s') (Q pre-scaled by log2e); packed cvt; permlane routing
      unsigned int F0 = cvtpk(exp2f(s0[0]), exp2f(s0[1]));
      unsigned int F1 = cvtpk(exp2f(s0[2]), exp2f(s0[3]));
      unsigned int G0 = cvtpk(exp2f(s1[0]), exp2f(s1[1]));
      unsigned int G1 = cvtpk(exp2f(s1[2]), exp2f(s1[3]));
      pl32swap(F0, G0); pl16swap(F0, G0);
      pl32swap(F1, G1); pl16swap(F1, G1);
      union { unsigned int u[4]; bf16x8 v; } pa;
      pa.u[0] = F0; pa.u[1] = F1; pa.u[2] = G0; pa.u[3] = G1;

      // PV for this q-slice (+ row-sum on MFMA pipe)
      __builtin_amdgcn_s_setprio(1);
#pragma unroll
      for (int dn = 0; dn < 4; ++dn)
        xacc[nt][dn] = __builtin_amdgcn_mfma_f32_16x16x32_bf16(pa.v, vk[dn], xacc[nt][dn], 0, 0, 0);
      xsum[nt] = __builtin_amdgcn_mfma_f32_16x16x32_bf16(pa.v, ones, xsum[nt], 0, 0, 0);
      __builtin_amdgcn_s_setprio(0);
    }
  }

  // epilogue: xsum cols replicated over fr -> every lane holds its rows' sums
  const int b = bh >> 4, h = bh & 15;
#pragma unroll
  for (int m = 0; m < 2; ++m) {
#pragma unroll
    for (int r = 0; r < 4; ++r) {
      const float inv = 1.f / xsum[m][r];
      const int s = q0 + m * 16 + fg * 4 + r;
      unsigned short* dst = Xa + ((size_t)(b * 2048 + s)) * 1024 + h * 64;
#pragma unroll
      for (int dn = 0; dn < 4; ++dn)
        dst[dn * 16 + fr] = f2bf(xacc[m][dn][r] * inv);
    }
  }
}

// ---------------------------------------------------------------- launch
extern "C" void kernel_launch(void* const* d_in, const int* in_sizes, int n_in,
                              void* d_out, int out_size, void* d_ws, size_t ws_size,
                              hipStream_t stream) {
  (void)in_sizes; (void)n_in; (void)out_size;
  const float* q  = (const float*)d_in[0];
  const float* k  = (const float*)d_in[1];
  const float* v  = (const float*)d_in[2];
  const float* Wq = (const float*)d_in[3];
  const float* bq = (const float*)d_in[4];
  const float* Wk = (const float*)d_in[5];
  const float* bk = (const float*)d_in[6];
  const float* Wv = (const float*)d_in[7];
  const float* bv = (const float*)d_in[8];
  const float* Wo = (const float*)d_in[9];
  const float* bo = (const float*)d_in[10];
  float* out = (float*)d_out;

  const size_t XB = (size_t)8192 * 1024;  // tokens x D
  const size_t WB = (size_t)1024 * 1024;
  const size_t need = (7 * XB + 4 * WB) * 2;
  if (ws_size < need) return;  // leaves output poisoned -> clear failure signal

  unsigned short* ws  = (unsigned short*)d_ws;
  unsigned short* xq  = ws;
  unsigned short* xk  = xq + XB;
  unsigned short* xv  = xk + XB;
  unsigned short* wqb = xv + XB;
  unsigned short* wkb = wqb + WB;
  unsigned short* wvb = wkb + WB;
  unsigned short* wob = wvb + WB;
  unsigned short* Qh  = wob + WB;
  unsigned short* Kh  = Qh + XB;
  unsigned short* Vt  = Kh + XB;
  unsigned short* Xa  = Vt + XB;

  // fp32 -> bf16 (2 batched launches)
  CvtJobs<3> jx; jx.in[0] = q; jx.in[1] = k; jx.in[2] = v;
  jx.out[0] = xq; jx.out[1] = xk; jx.out[2] = xv; jx.n = (int)XB;
  cvt_batch<3><<<dim3(XB / 1024, 3), 256, 0, stream>>>(jx);
  CvtJobs<4> jw; jw.in[0] = Wq; jw.in[1] = Wk; jw.in[2] = Wv; jw.in[3] = Wo;
  jw.out[0] = wqb; jw.out[1] = wkb; jw.out[2] = wvb; jw.out[3] = wob; jw.n = (int)WB;
  cvt_batch<4><<<dim3(WB / 1024, 4), 256, 0, stream>>>(jw);

  // Q&K projections in one launch (z selects); V transposed so V^T coalesces
  gemm_bt<4><<<dim3(8, 64, 2), 256, 0, stream>>>(xq, wqb, bq, bk, Qh, 8192, 1024, 1024);
  gemm_bt<2><<<dim3(64, 8), 256, 0, stream>>>(wvb, xv, bv, nullptr, Vt, 1024, 8192, 1024);

  // attention (barrier-free, LDS-free, 4 waves/SIMD occupancy, XCD-swizzled)
  attn_kernel<<<dim3(1024), 256, 0, stream>>>(Qh, Kh, Vt, Xa);

  // output projection (fp32 out + bias)
  gemm_bt<3><<<dim3(8, 64), 256, 0, stream>>>(Xa, wob, bo, nullptr, out, 8192, 1024, 1024);
}